// Round 8
// baseline (243.110 us; speedup 1.0000x reference)
//
#include <hip/hip_runtime.h>
#include <math.h>

typedef __attribute__((ext_vector_type(8))) short short8;
typedef __attribute__((ext_vector_type(4))) float f32x4;

__device__ __forceinline__ short f2bf(float f) {
    union { float f; unsigned u; } v; v.f = f;
    unsigned r = v.u + 0x7fff + ((v.u >> 16) & 1);
    return (short)(r >> 16);
}

// async global->LDS, 16B per lane; lds base must be wave-uniform.
__device__ __forceinline__ void gload16(const short* g, short* l) {
    __builtin_amdgcn_global_load_lds(
        (const __attribute__((address_space(1))) unsigned int*)g,
        (__attribute__((address_space(3))) unsigned int*)l,
        16, 0, 0);
}

// ---------------------------------------------------------------------------
// prep: x->bf16 (blocks 0..2047), weight transposes (2048..5119), bias pack.
// ---------------------------------------------------------------------------
__global__ __launch_bounds__(256) void prep_kernel(
    const float* __restrict__ x, short* __restrict__ xb,
    const float* __restrict__ Wq, const float* __restrict__ Wk,
    const float* __restrict__ Wv, const float* __restrict__ Wo,
    const float* __restrict__ W1, const float* __restrict__ W2,
    short* __restrict__ Wqkv_t, short* __restrict__ Wo_t,
    short* __restrict__ W1_t, short* __restrict__ W2_t,
    const float* __restrict__ bq, const float* __restrict__ bk,
    const float* __restrict__ bv, float* __restrict__ qbias)
{
    int bid = blockIdx.x;
    if (bid < 2048) {
        int i = (bid * 256 + threadIdx.x) * 4;
        float4 v = *reinterpret_cast<const float4*>(&x[i]);
        short4 o;
        o.x = f2bf(v.x); o.y = f2bf(v.y); o.z = f2bf(v.z); o.w = f2bf(v.w);
        *reinterpret_cast<short4*>(&xb[i]) = o;
        return;
    }
    if (bid < 5120) {
        int t = bid - 2048;
        const float* W; short* Wt; int K, N, nbx, loc;
        if (t < 1024) {
            int j = t >> 8; loc = t & 255; K = 512; N = 512; nbx = 16;
            W  = (j == 0) ? Wq : (j == 1) ? Wk : (j == 2) ? Wv : Wo;
            Wt = (j == 0) ? Wqkv_t : (j == 1) ? Wqkv_t + 512 * 512
               : (j == 2) ? Wqkv_t + 1024 * 512 : Wo_t;
        } else if (t < 2048) {
            loc = t - 1024; W = W1; Wt = W1_t; K = 512; N = 2048; nbx = 16;
        } else {
            loc = t - 2048; W = W2; Wt = W2_t; K = 2048; N = 512; nbx = 64;
        }
        int k0 = (loc % nbx) * 32, n0 = (loc / nbx) * 32;
        __shared__ float tl[32][33];
        int tx = threadIdx.x & 31, ty = threadIdx.x >> 5;
#pragma unroll
        for (int r = ty; r < 32; r += 8)
            tl[r][tx] = W[(size_t)(k0 + r) * N + n0 + tx];
        __syncthreads();
#pragma unroll
        for (int r = ty; r < 32; r += 8)
            Wt[(size_t)(n0 + r) * K + k0 + tx] = f2bf(tl[tx][r]);
        return;
    }
    {
        int i = (bid - 5120) * 256 + threadIdx.x;
        if (i < 1536)
            qbias[i] = (i < 512) ? bq[i] : (i < 1024 ? bk[i - 512] : bv[i - 1024]);
    }
}

// ---------------------------------------------------------------------------
// Single 64x64 score tile (tt > si strictly, unmasked): Q s-block si,
// K t-block tt -> heat. No LDS, no barriers; backfills GEMM kernels.
// ---------------------------------------------------------------------------
__device__ __forceinline__ void scores_tile(
    const short* __restrict__ QKV, float* __restrict__ heat,
    int hb, int si, int tt)
{
    constexpr int S = 2048, LD = 1536;
    int tid = threadIdx.x, wid = tid >> 6, lane = tid & 63;
    int g = lane >> 4, c = lane & 15, g4 = g * 4;
    int h = hb >> 1, b = hb & 1;
    int sglob = si * 64 + wid * 16 + c;
    const short* qp = QKV + (size_t)(b * S + sglob) * LD + h * 64 + g * 8;
    short8 q0 = *(const short8*)qp, q1 = *(const short8*)(qp + 32);
    const short* kb = QKV + (size_t)(b * S + tt * 64) * LD + 512 + h * 64;
#pragma unroll
    for (int ni = 0; ni < 4; ++ni) {
        short8 k0 = *(const short8*)(kb + (size_t)(ni * 16 + c) * LD + g * 8);
        short8 k1 = *(const short8*)(kb + (size_t)(ni * 16 + c) * LD + 32 + g * 8);
        f32x4 sacc = (f32x4){0.f, 0.f, 0.f, 0.f};
        sacc = __builtin_amdgcn_mfma_f32_16x16x32_bf16(k0, q0, sacc, 0, 0, 0);
        sacc = __builtin_amdgcn_mfma_f32_16x16x32_bf16(k1, q1, sacc, 0, 0, 0);
        __builtin_nontemporal_store(sacc,
            (f32x4*)&heat[((size_t)hb * S + sglob) * S + tt * 64 + ni * 16 + g4]);
    }
}

// ---------------------------------------------------------------------------
// GEMM body (single-buffered, 2 barriers/K-iter, gload_lds staging).
// BM = MI*32, BN = NI*32, BK = 64, 4 waves (2x2).
// ---------------------------------------------------------------------------
template<int MI, int NI>
__device__ __forceinline__ void gemm_body(
    short* __restrict__ smem,
    const short* __restrict__ A, int lda,
    const short* __restrict__ Bt, int ldb,
    const float* __restrict__ bias, const float* __restrict__ resid,
    float* __restrict__ Cf, short* __restrict__ Cb,
    int N, int K, int relu, int bx, int byy)
{
    constexpr int BM = MI * 32, BN = NI * 32;
    short* Ash = smem;
    short* Bsh = smem + BM * 64;
    int tid = threadIdx.x, wid = tid >> 6, lane = tid & 63;
    int g = lane >> 4, c = lane & 15;
    int wm = wid >> 1, wn = wid & 1;
    size_t m0 = (size_t)bx * BM, n0 = (size_t)byy * BN;
    int lrow = lane >> 3, lcol = (lane & 7) * 8;

    f32x4 acc[MI][NI];
#pragma unroll
    for (int i = 0; i < MI; ++i)
#pragma unroll
        for (int j = 0; j < NI; ++j)
            acc[i][j] = (f32x4){0.f, 0.f, 0.f, 0.f};

    for (int k0 = 0; k0 < K; k0 += 64) {
        __syncthreads();
#pragma unroll
        for (int i = 0; i < MI; ++i) {
            int chunk = wid * MI + i; int row = chunk * 8 + lrow;
            gload16(A + (m0 + row) * lda + k0 + lcol, Ash + chunk * 512);
        }
#pragma unroll
        for (int i = 0; i < NI; ++i) {
            int chunk = wid * NI + i; int row = chunk * 8 + lrow;
            gload16(Bt + (n0 + row) * ldb + k0 + lcol, Bsh + chunk * 512);
        }
        __syncthreads();

        short8 a[MI][2], b[NI][2];
#pragma unroll
        for (int kc = 0; kc < 2; ++kc) {
#pragma unroll
            for (int mi = 0; mi < MI; ++mi)
                a[mi][kc] = *(const short8*)&Ash[(wm * MI * 16 + mi * 16 + c) * 64 + kc * 32 + g * 8];
#pragma unroll
            for (int ni = 0; ni < NI; ++ni)
                b[ni][kc] = *(const short8*)&Bsh[(wn * NI * 16 + ni * 16 + c) * 64 + kc * 32 + g * 8];
        }
#pragma unroll
        for (int kc = 0; kc < 2; ++kc)
#pragma unroll
            for (int mi = 0; mi < MI; ++mi)
#pragma unroll
                for (int ni = 0; ni < NI; ++ni)
                    acc[mi][ni] = __builtin_amdgcn_mfma_f32_16x16x32_bf16(
                        a[mi][kc], b[ni][kc], acc[mi][ni], 0, 0, 0);
    }

#pragma unroll
    for (int mi = 0; mi < MI; ++mi)
#pragma unroll
        for (int ni = 0; ni < NI; ++ni)
#pragma unroll
            for (int r = 0; r < 4; ++r) {
                size_t m = m0 + wm * (MI * 16) + mi * 16 + g * 4 + r;
                size_t n = n0 + wn * (NI * 16) + ni * 16 + c;
                float v = acc[mi][ni][r];
                if (bias)  v += bias[n];
                if (resid) v += resid[m * N + n];
                if (relu)  v = fmaxf(v, 0.f);
                if (Cf) Cf[m * N + n] = v;
                if (Cb) Cb[m * N + n] = f2bf(v);
            }
}

// ---------------------------------------------------------------------------
// GEMM + optional embedded single-tile score-streaming blocks (1D grid).
// id < ngemm: GEMM tile (id%gx, id/gx); else scores unit u0 + (id-ngemm).
// u in [0,7936): hb = u/496; triangular decode (si, tt>si).
// ---------------------------------------------------------------------------
template<int MI, int NI>
__global__ __launch_bounds__(256) void gemm_sc(
    const short* __restrict__ A, int lda,
    const short* __restrict__ Bt, int ldb,
    const float* __restrict__ bias, const float* __restrict__ resid,
    float* __restrict__ Cf, short* __restrict__ Cb,
    int N, int K, int relu, int gx, int ngemm,
    const short* __restrict__ QKV, float* __restrict__ heat, int u0)
{
    __shared__ short smem[(MI + NI) * 32 * 64];
    int id = blockIdx.x;
    if (id < ngemm) {
        gemm_body<MI, NI>(smem, A, lda, Bt, ldb, bias, resid, Cf, Cb,
                          N, K, relu, id % gx, id / gx);
    } else {
        int u = u0 + (id - ngemm);
        int hb = u / 496, rem = u % 496;
        int si = 0;
        while (rem >= 31 - si) { rem -= 31 - si; ++si; }
        scores_tile(QKV, heat, hb, si, si + 1 + rem);
    }
}

// ---------------------------------------------------------------------------
// Flash attention, causal tiles (+ optional score-only streaming phase for
// the fallback path). Swapped-operand QK^T; 1 barrier/causal tile; diagonal-
// only masking; XCD-chunked 1D grid of 512 blocks.
// ---------------------------------------------------------------------------
__global__ __launch_bounds__(256) void attn_kernel(
    const short* __restrict__ QKV,
    float* __restrict__ heat,
    short* __restrict__ wv, int do_stream)
{
    constexpr int S = 2048, LD = 1536;
    __shared__ short Vt[2][64][72];    // [buf][v][t]
    __shared__ short Pl[4][16][72];    // per-wave P, [s][t]

    int tid = threadIdx.x, wid = tid >> 6, lane = tid & 63;
    int g = lane >> 4, c = lane & 15, g4 = g * 4;
    int id = blockIdx.x;
    int xcd = id & 7, k = id >> 3;
    int hb = (xcd << 1) | (k >> 5);
    int sb = k & 31;
    int by = (sb & 1) ? (31 - (sb >> 1)) : (sb >> 1);
    int h = hb >> 1, b = hb & 1;
    int s0 = by * 64, sbase = s0 + wid * 16, sglob = sbase + c;

    const short* qp = QKV + (size_t)(b * S + sglob) * LD + h * 64 + g * 8;
    short8 q0 = *(const short8*)qp, q1 = *(const short8*)(qp + 32);

    f32x4 o[4];
#pragma unroll
    for (int ni = 0; ni < 4; ++ni) o[ni] = (f32x4){0.f, 0.f, 0.f, 0.f};
    float m_run = -1e30f, l_run = 0.f;

    const short* kb_base = QKV + (size_t)b * S * LD + 512 + h * 64;
    int vrow = tid >> 2, vch = tid & 3;
    const short* vb_base = QKV + (size_t)b * S * LD + 1024 + h * 64 + vch * 16;

    auto loadK = [&](int tt, short8 dst[4][2]) {
#pragma unroll
        for (int ni = 0; ni < 4; ++ni)
#pragma unroll
            for (int kc = 0; kc < 2; ++kc)
                dst[ni][kc] = *(const short8*)(kb_base +
                    (size_t)(tt * 64 + ni * 16 + c) * LD + kc * 32 + g * 8);
    };

    short8 kcur[4][2];
    loadK(0, kcur);
    short8 va, vb2;
    {
        const short* vp = vb_base + (size_t)vrow * LD;
        va = *(const short8*)vp; vb2 = *(const short8*)(vp + 8);
    }

    // ---- causal phase: tiles 0..by, 1 barrier/tile ----
    for (int tt = 0; tt <= by; ++tt) {
        int cur = tt & 1;
#pragma unroll
        for (int j = 0; j < 8; ++j) Vt[cur][vch * 16 + j][vrow] = va[j];
#pragma unroll
        for (int j = 0; j < 8; ++j) Vt[cur][vch * 16 + 8 + j][vrow] = vb2[j];

        short8 knext[4][2], vna, vnb;
        bool more = do_stream ? (tt < 31) : (tt < by);
        if (more) loadK(tt + 1, knext);
        if (tt < by) {
            const short* vp = vb_base + (size_t)((tt + 1) * 64 + vrow) * LD;
            vna = *(const short8*)vp; vnb = *(const short8*)(vp + 8);
        }

        int t0 = tt * 64;
        f32x4 sacc[4];
#pragma unroll
        for (int ni = 0; ni < 4; ++ni) {
            sacc[ni] = (f32x4){0.f, 0.f, 0.f, 0.f};
            sacc[ni] = __builtin_amdgcn_mfma_f32_16x16x32_bf16(kcur[ni][0], q0, sacc[ni], 0, 0, 0);
            sacc[ni] = __builtin_amdgcn_mfma_f32_16x16x32_bf16(kcur[ni][1], q1, sacc[ni], 0, 0, 0);
        }
#pragma unroll
        for (int ni = 0; ni < 4; ++ni)
            __builtin_nontemporal_store(sacc[ni],
                (f32x4*)&heat[((size_t)hb * S + sglob) * S + t0 + ni * 16 + g4]);

        float tm = -1e30f;
        if (tt == by) {
#pragma unroll
            for (int ni = 0; ni < 4; ++ni)
#pragma unroll
                for (int r = 0; r < 4; ++r) {
                    int t = t0 + ni * 16 + g4 + r;
                    float v = (t <= sglob) ? sacc[ni][r] : -1e30f;
                    sacc[ni][r] = v;
                    tm = fmaxf(tm, v);
                }
        } else {
#pragma unroll
            for (int ni = 0; ni < 4; ++ni)
#pragma unroll
                for (int r = 0; r < 4; ++r)
                    tm = fmaxf(tm, sacc[ni][r]);
        }
        tm = fmaxf(tm, __shfl_xor(tm, 16));
        tm = fmaxf(tm, __shfl_xor(tm, 32));

        float mn = fmaxf(m_run, tm);
        float sc = __expf(m_run - mn);
        m_run = mn;
        float ps = 0.f;
#pragma unroll
        for (int ni = 0; ni < 4; ++ni)
#pragma unroll
            for (int r = 0; r < 4; ++r) {
                float p = __expf(sacc[ni][r] - mn);
                sacc[ni][r] = p;
                ps += p;
            }
        ps += __shfl_xor(ps, 16);
        ps += __shfl_xor(ps, 32);
        l_run = l_run * sc + ps;

        float scr[4];
#pragma unroll
        for (int r = 0; r < 4; ++r) scr[r] = __shfl(sc, g4 + r, 64);
#pragma unroll
        for (int ni = 0; ni < 4; ++ni)
#pragma unroll
            for (int r = 0; r < 4; ++r)
                o[ni][r] *= scr[r];

#pragma unroll
        for (int ni = 0; ni < 4; ++ni) {
            short4 pw;
            pw.x = f2bf(sacc[ni][0]); pw.y = f2bf(sacc[ni][1]);
            pw.z = f2bf(sacc[ni][2]); pw.w = f2bf(sacc[ni][3]);
            *reinterpret_cast<short4*>(&Pl[wid][c][ni * 16 + g4]) = pw;
        }

        __syncthreads();

        short8 pa0 = *reinterpret_cast<const short8*>(&Pl[wid][c][g * 8]);
        short8 pa1 = *reinterpret_cast<const short8*>(&Pl[wid][c][32 + g * 8]);
#pragma unroll
        for (int ni = 0; ni < 4; ++ni) {
            short8 vb0 = *reinterpret_cast<const short8*>(&Vt[cur][ni * 16 + c][g * 8]);
            short8 vb1 = *reinterpret_cast<const short8*>(&Vt[cur][ni * 16 + c][32 + g * 8]);
            o[ni] = __builtin_amdgcn_mfma_f32_16x16x32_bf16(pa0, vb0, o[ni], 0, 0, 0);
            o[ni] = __builtin_amdgcn_mfma_f32_16x16x32_bf16(pa1, vb1, o[ni], 0, 0, 0);
        }

        if (more) {
#pragma unroll
            for (int ni = 0; ni < 4; ++ni)
#pragma unroll
                for (int kc = 0; kc < 2; ++kc)
                    kcur[ni][kc] = knext[ni][kc];
        }
        if (tt < by) { va = vna; vb2 = vnb; }
    }

    // ---- fallback-only: score-only streaming phase ----
    if (do_stream) {
        for (int tt = by + 1; tt < 32; ++tt) {
            int t0 = tt * 64;
            short8 knext[4][2];
            if (tt < 31) loadK(tt + 1, knext);
            f32x4 sacc[4];
#pragma unroll
            for (int ni = 0; ni < 4; ++ni) {
                sacc[ni] = (f32x4){0.f, 0.f, 0.f, 0.f};
                sacc[ni] = __builtin_amdgcn_mfma_f32_16x16x32_bf16(kcur[ni][0], q0, sacc[ni], 0, 0, 0);
                sacc[ni] = __builtin_amdgcn_mfma_f32_16x16x32_bf16(kcur[ni][1], q1, sacc[ni], 0, 0, 0);
            }
#pragma unroll
            for (int ni = 0; ni < 4; ++ni)
                __builtin_nontemporal_store(sacc[ni],
                    (f32x4*)&heat[((size_t)hb * S + sglob) * S + t0 + ni * 16 + g4]);
            if (tt < 31) {
#pragma unroll
                for (int ni = 0; ni < 4; ++ni)
#pragma unroll
                    for (int kc = 0; kc < 2; ++kc)
                        kcur[ni][kc] = knext[ni][kc];
            }
        }
    }

    float linv[4];
#pragma unroll
    for (int r = 0; r < 4; ++r) linv[r] = 1.0f / __shfl(l_run, g4 + r, 64);
#pragma unroll
    for (int ni = 0; ni < 4; ++ni)
#pragma unroll
        for (int r = 0; r < 4; ++r) {
            float v = o[ni][r] * linv[r];
            wv[(size_t)(b * S + sbase + g4 + r) * 512 + h * 64 + ni * 16 + c] = f2bf(v);
        }
}

// ---------------------------------------------------------------------------
// LayerNorm over last dim 512; optional secondary bf16 output.
// ---------------------------------------------------------------------------
__device__ __forceinline__ float block_sum256(float v, float* sm) {
#pragma unroll
    for (int off = 32; off; off >>= 1) v += __shfl_down(v, off);
    __syncthreads();
    if ((threadIdx.x & 63) == 0) sm[threadIdx.x >> 6] = v;
    __syncthreads();
    return sm[0] + sm[1] + sm[2] + sm[3];
}

__global__ __launch_bounds__(256) void ln_kernel(
    const float* __restrict__ in, const float* __restrict__ g,
    const float* __restrict__ bta, float* __restrict__ outf,
    short* __restrict__ outb)
{
    __shared__ float sm[4];
    int row = blockIdx.x, tid = threadIdx.x;
    const float* r = in + (size_t)row * 512;
    float v0 = r[tid], v1 = r[tid + 256];
    float mu = block_sum256(v0 + v1, sm) * (1.f / 512.f);
    float d0 = v0 - mu, d1 = v1 - mu;
    float var = block_sum256(d0 * d0 + d1 * d1, sm) * (1.f / 512.f);
    float rs = rsqrtf(var + 1e-5f);
    float o0 = d0 * rs * g[tid] + bta[tid];
    float o1 = d1 * rs * g[tid + 256] + bta[tid + 256];
    outf[(size_t)row * 512 + tid]       = o0;
    outf[(size_t)row * 512 + tid + 256] = o1;
    if (outb) {
        outb[(size_t)row * 512 + tid]       = f2bf(o0);
        outb[(size_t)row * 512 + tid + 256] = f2bf(o1);
    }
}

// ---------------------------------------------------------------------------
extern "C" void kernel_launch(void* const* d_in, const int* in_sizes, int n_in,
                              void* d_out, int out_size, void* d_ws, size_t ws_size,
                              hipStream_t stream)
{
    const float* x    = (const float*)d_in[0];
    const float* Wq   = (const float*)d_in[1];
    const float* bq   = (const float*)d_in[2];
    const float* Wk   = (const float*)d_in[3];
    const float* bk   = (const float*)d_in[4];
    const float* Wv   = (const float*)d_in[5];
    const float* bv   = (const float*)d_in[6];
    const float* Wo   = (const float*)d_in[7];
    const float* bo   = (const float*)d_in[8];
    const float* W1   = (const float*)d_in[9];
    const float* b1   = (const float*)d_in[10];
    const float* W2   = (const float*)d_in[11];
    const float* b2   = (const float*)d_in[12];
    const float* ln1g = (const float*)d_in[13];
    const float* ln1b = (const float*)d_in[14];
    const float* ln2g = (const float*)d_in[15];
    const float* ln2b = (const float*)d_in[16];

    const int T = 4096;
    char* w = (char*)d_ws;
    float* out_x2 = (float*)d_out;
    float* heat   = out_x2 + (size_t)T * 512;

    bool big = ws_size >= (size_t)60823552;

    if (big) {
        // --- overlapped layout (58 MB) ---
        short* xb     = (short*)(w);                    // [0,4M)
        short* QKVb   = (short*)(w + 4194304);          // [4M,16M)
        short* wvb    = (short*)(w + 16777216);         // [16M,20M)
        float* tmpf   = (float*)(w + 20971520);         // [20M,28M)  dead after LN1
        short* hidb   = (short*)(w + 16777216);         // [16M,32M)  after wvb/tmpf dead
        float* x1f    = (float*)(w + 33554432);         // [32M,40M)
        short* x1b    = (short*)(w + 41943040);         // [40M,44M)
        float* tmpf2  = (float*)(w + 46137344);         // [44M,52M)
        short* Wqkv_t = (short*)(w + 54525952);
        short* Wo_t   = (short*)(w + 56098816);
        short* W1_t   = (short*)(w + 56623104);
        short* W2_t   = (short*)(w + 58720256);
        float* qbias  = (float*)(w + 60817408);

        prep_kernel<<<dim3(5126), 256, 0, stream>>>(
            x, xb, Wq, Wk, Wv, Wo, W1, W2,
            Wqkv_t, Wo_t, W1_t, W2_t, bq, bk, bv, qbias);

        gemm_sc<2, 4><<<dim3(768), 256, 0, stream>>>(
            xb, 512, Wqkv_t, 512, qbias, nullptr, nullptr, QKVb,
            1536, 512, 0, 64, 768, nullptr, nullptr, 0);

        attn_kernel<<<dim3(512), 256, 0, stream>>>(QKVb, heat, wvb, 0);

        // Wo + residual, + 1150 score tiles
        gemm_sc<2, 2><<<dim3(512 + 1150), 256, 0, stream>>>(
            wvb, 512, Wo_t, 512, bo, x, tmpf, nullptr,
            512, 512, 0, 64, 512, QKVb, heat, 0);
        ln_kernel<<<dim3(T), 256, 0, stream>>>(tmpf, ln1g, ln1b, x1f, x1b);

        // FFN1, + 2900 score tiles
        gemm_sc<2, 4><<<dim3(1024 + 2900), 256, 0, stream>>>(
            x1b, 512, W1_t, 512, b1, nullptr, nullptr, hidb,
            2048, 512, 1, 64, 1024, QKVb, heat, 1150);

        // FFN2 + residual, + 3886 score tiles
        gemm_sc<2, 2><<<dim3(512 + 3886), 256, 0, stream>>>(
            hidb, 2048, W2_t, 2048, b2, x1f, tmpf2, nullptr,
            512, 2048, 0, 64, 512, QKVb, heat, 4050);
        ln_kernel<<<dim3(T), 256, 0, stream>>>(tmpf2, ln2g, ln2b, out_x2, nullptr);
    } else {
        // --- fallback: exact R7 behavior (48.2 MB layout) ---
        short* xb     = (short*)(w);
        short* QKVb   = (short*)(w + 4194304);
        short* wvb    = (short*)(w + 16777216);
        float* tmpf   = (float*)(w + 20971520);
        float* x1f    = (float*)(w + 29360128);
        short* x1b    = (short*)(w + 37748736);
        short* Wqkv_t = (short*)(w + 41943040);
        short* Wo_t   = (short*)(w + 43515904);
        short* W1_t   = (short*)(w + 44040192);
        short* W2_t   = (short*)(w + 46137344);
        float* qbias  = (float*)(w + 48234496);
        short* hidb   = (short*)(w);   // aliases xb+QKVb (dead by FFN1)

        prep_kernel<<<dim3(5126), 256, 0, stream>>>(
            x, xb, Wq, Wk, Wv, Wo, W1, W2,
            Wqkv_t, Wo_t, W1_t, W2_t, bq, bk, bv, qbias);

        gemm_sc<2, 4><<<dim3(768), 256, 0, stream>>>(
            xb, 512, Wqkv_t, 512, qbias, nullptr, nullptr, QKVb,
            1536, 512, 0, 64, 768, nullptr, nullptr, 0);

        attn_kernel<<<dim3(512), 256, 0, stream>>>(QKVb, heat, wvb, 1);

        gemm_sc<2, 2><<<dim3(512), 256, 0, stream>>>(
            wvb, 512, Wo_t, 512, bo, x, tmpf, nullptr,
            512, 512, 0, 64, 512, nullptr, nullptr, 0);
        ln_kernel<<<dim3(T), 256, 0, stream>>>(tmpf, ln1g, ln1b, x1f, x1b);

        gemm_sc<2, 4><<<dim3(1024), 256, 0, stream>>>(
            x1b, 512, W1_t, 512, b1, nullptr, nullptr, hidb,
            2048, 512, 1, 64, 1024, nullptr, nullptr, 0);
        gemm_sc<2, 2><<<dim3(512), 256, 0, stream>>>(
            hidb, 2048, W2_t, 2048, b2, x1f, tmpf, nullptr,
            512, 2048, 0, 64, 512, nullptr, nullptr, 0);
        ln_kernel<<<dim3(T), 256, 0, stream>>>(tmpf, ln2g, ln2b, out_x2, nullptr);
    }
}

// Round 9
// 238.682 us; speedup vs baseline: 1.0186x; 1.0186x over previous
//
#include <hip/hip_runtime.h>
#include <math.h>

typedef __attribute__((ext_vector_type(8))) short short8;
typedef __attribute__((ext_vector_type(4))) float f32x4;

__device__ __forceinline__ short f2bf(float f) {
    union { float f; unsigned u; } v; v.f = f;
    unsigned r = v.u + 0x7fff + ((v.u >> 16) & 1);
    return (short)(r >> 16);
}

// async global->LDS, 16B per lane; lds base must be wave-uniform.
__device__ __forceinline__ void gload16(const short* g, short* l) {
    __builtin_amdgcn_global_load_lds(
        (const __attribute__((address_space(1))) unsigned int*)g,
        (__attribute__((address_space(3))) unsigned int*)l,
        16, 0, 0);
}

// ---------------------------------------------------------------------------
// prep: x->bf16 (blocks 0..2047), weight transposes (2048..5119), bias pack.
// ---------------------------------------------------------------------------
__global__ __launch_bounds__(256) void prep_kernel(
    const float* __restrict__ x, short* __restrict__ xb,
    const float* __restrict__ Wq, const float* __restrict__ Wk,
    const float* __restrict__ Wv, const float* __restrict__ Wo,
    const float* __restrict__ W1, const float* __restrict__ W2,
    short* __restrict__ Wqkv_t, short* __restrict__ Wo_t,
    short* __restrict__ W1_t, short* __restrict__ W2_t,
    const float* __restrict__ bq, const float* __restrict__ bk,
    const float* __restrict__ bv, float* __restrict__ qbias)
{
    int bid = blockIdx.x;
    if (bid < 2048) {
        int i = (bid * 256 + threadIdx.x) * 4;
        float4 v = *reinterpret_cast<const float4*>(&x[i]);
        short4 o;
        o.x = f2bf(v.x); o.y = f2bf(v.y); o.z = f2bf(v.z); o.w = f2bf(v.w);
        *reinterpret_cast<short4*>(&xb[i]) = o;
        return;
    }
    if (bid < 5120) {
        int t = bid - 2048;
        const float* W; short* Wt; int K, N, nbx, loc;
        if (t < 1024) {
            int j = t >> 8; loc = t & 255; K = 512; N = 512; nbx = 16;
            W  = (j == 0) ? Wq : (j == 1) ? Wk : (j == 2) ? Wv : Wo;
            Wt = (j == 0) ? Wqkv_t : (j == 1) ? Wqkv_t + 512 * 512
               : (j == 2) ? Wqkv_t + 1024 * 512 : Wo_t;
        } else if (t < 2048) {
            loc = t - 1024; W = W1; Wt = W1_t; K = 512; N = 2048; nbx = 16;
        } else {
            loc = t - 2048; W = W2; Wt = W2_t; K = 2048; N = 512; nbx = 64;
        }
        int k0 = (loc % nbx) * 32, n0 = (loc / nbx) * 32;
        __shared__ float tl[32][33];
        int tx = threadIdx.x & 31, ty = threadIdx.x >> 5;
#pragma unroll
        for (int r = ty; r < 32; r += 8)
            tl[r][tx] = W[(size_t)(k0 + r) * N + n0 + tx];
        __syncthreads();
#pragma unroll
        for (int r = ty; r < 32; r += 8)
            Wt[(size_t)(n0 + r) * K + k0 + tx] = f2bf(tl[tx][r]);
        return;
    }
    {
        int i = (bid - 5120) * 256 + threadIdx.x;
        if (i < 1536)
            qbias[i] = (i < 512) ? bq[i] : (i < 1024 ? bk[i - 512] : bv[i - 1024]);
    }
}

// ---------------------------------------------------------------------------
// bf16 MFMA GEMM (single-buffered, 2 barriers/K-iter, gload_lds staging).
// BM = MI*32, BN = NI*32, BK = 64, 4 waves (2x2).
// ---------------------------------------------------------------------------
template<int MI, int NI>
__global__ __launch_bounds__(256) void gemm2(
    const short* __restrict__ A, int lda,
    const short* __restrict__ Bt, int ldb,
    const float* __restrict__ bias,
    const float* __restrict__ resid,
    float* __restrict__ Cf, short* __restrict__ Cb,
    int N, int K, int relu)
{
    constexpr int BM = MI * 32;
    constexpr int BN = NI * 32;
    __shared__ short Ash[BM * 64];
    __shared__ short Bsh[BN * 64];
    int tid = threadIdx.x;
    int wid = tid >> 6, lane = tid & 63;
    int g = lane >> 4, c = lane & 15;
    int wm = wid >> 1, wn = wid & 1;
    size_t m0 = (size_t)blockIdx.x * BM;
    size_t n0 = (size_t)blockIdx.y * BN;
    int lrow = lane >> 3;          // 0..7
    int lcol = (lane & 7) * 8;     // shorts (16B granule)

    f32x4 acc[MI][NI];
#pragma unroll
    for (int i = 0; i < MI; ++i)
#pragma unroll
        for (int j = 0; j < NI; ++j)
            acc[i][j] = (f32x4){0.f, 0.f, 0.f, 0.f};

    constexpr int WM = MI / 2 == 0 ? MI : MI;   // per-wave M frags = MI (wm splits rows)
    for (int k0 = 0; k0 < K; k0 += 64) {
        __syncthreads();
#pragma unroll
        for (int i = 0; i < MI; ++i) {
            int chunk = wid * MI + i; int row = chunk * 8 + lrow;
            gload16(A + (m0 + row) * lda + k0 + lcol, Ash + chunk * 512);
        }
#pragma unroll
        for (int i = 0; i < NI; ++i) {
            int chunk = wid * NI + i; int row = chunk * 8 + lrow;
            gload16(Bt + (n0 + row) * ldb + k0 + lcol, Bsh + chunk * 512);
        }
        __syncthreads();

        short8 a[MI][2], b[NI][2];
#pragma unroll
        for (int kc = 0; kc < 2; ++kc) {
#pragma unroll
            for (int mi = 0; mi < MI; ++mi)
                a[mi][kc] = *(const short8*)&Ash[(wm * MI * 16 + mi * 16 + c) * 64 + kc * 32 + g * 8];
#pragma unroll
            for (int ni = 0; ni < NI; ++ni)
                b[ni][kc] = *(const short8*)&Bsh[(wn * NI * 16 + ni * 16 + c) * 64 + kc * 32 + g * 8];
        }
#pragma unroll
        for (int kc = 0; kc < 2; ++kc)
#pragma unroll
            for (int mi = 0; mi < MI; ++mi)
#pragma unroll
                for (int ni = 0; ni < NI; ++ni)
                    acc[mi][ni] = __builtin_amdgcn_mfma_f32_16x16x32_bf16(
                        a[mi][kc], b[ni][kc], acc[mi][ni], 0, 0, 0);
    }

#pragma unroll
    for (int mi = 0; mi < MI; ++mi)
#pragma unroll
        for (int ni = 0; ni < NI; ++ni)
#pragma unroll
            for (int r = 0; r < 4; ++r) {
                size_t m = m0 + wm * (MI * 16) + mi * 16 + g * 4 + r;
                size_t n = n0 + wn * (NI * 16) + ni * 16 + c;
                float v = acc[mi][ni][r];
                if (bias)  v += bias[n];
                if (resid) v += resid[m * N + n];
                if (relu)  v = fmaxf(v, 0.f);
                if (Cf) Cf[m * N + n] = v;
                if (Cb) Cb[m * N + n] = f2bf(v);
            }
}

// ---------------------------------------------------------------------------
// Fused flash attention + full heatmap (R7 structure). Swapped-operand QK^T;
// causal phase 1 barrier/tile (dbuf V, reg prefetch, diag-only mask);
// score-only phase barrier-free. 1D grid 512 blocks, XCD-chunked.
// ---------------------------------------------------------------------------
__global__ __launch_bounds__(256) void attn_kernel(
    const short* __restrict__ QKV,
    float* __restrict__ heat,
    short* __restrict__ wv)
{
    constexpr int S = 2048, LD = 1536;
    __shared__ short Vt[2][64][72];    // [buf][v][t]
    __shared__ short Pl[4][16][72];    // per-wave P, [s][t]

    int tid = threadIdx.x, wid = tid >> 6, lane = tid & 63;
    int g = lane >> 4, c = lane & 15, g4 = g * 4;
    int id = blockIdx.x;
    int xcd = id & 7, k = id >> 3;
    int hb = (xcd << 1) | (k >> 5);
    int sb = k & 31;
    int by = (sb & 1) ? (31 - (sb >> 1)) : (sb >> 1);
    int h = hb >> 1, b = hb & 1;
    int s0 = by * 64, sbase = s0 + wid * 16, sglob = sbase + c;

    const short* qp = QKV + (size_t)(b * S + sglob) * LD + h * 64 + g * 8;
    short8 q0 = *(const short8*)qp, q1 = *(const short8*)(qp + 32);

    f32x4 o[4];
#pragma unroll
    for (int ni = 0; ni < 4; ++ni) o[ni] = (f32x4){0.f, 0.f, 0.f, 0.f};
    float m_run = -1e30f, l_run = 0.f;

    const short* kb_base = QKV + (size_t)b * S * LD + 512 + h * 64;
    int vrow = tid >> 2, vch = tid & 3;
    const short* vb_base = QKV + (size_t)b * S * LD + 1024 + h * 64 + vch * 16;

    auto loadK = [&](int tt, short8 dst[4][2]) {
#pragma unroll
        for (int ni = 0; ni < 4; ++ni)
#pragma unroll
            for (int kc = 0; kc < 2; ++kc)
                dst[ni][kc] = *(const short8*)(kb_base +
                    (size_t)(tt * 64 + ni * 16 + c) * LD + kc * 32 + g * 8);
    };

    short8 kcur[4][2];
    loadK(0, kcur);
    short8 va, vb2;
    {
        const short* vp = vb_base + (size_t)vrow * LD;
        va = *(const short8*)vp; vb2 = *(const short8*)(vp + 8);
    }

    // ---- causal phase: tiles 0..by, 1 barrier/tile ----
    for (int tt = 0; tt <= by; ++tt) {
        int cur = tt & 1;
#pragma unroll
        for (int j = 0; j < 8; ++j) Vt[cur][vch * 16 + j][vrow] = va[j];
#pragma unroll
        for (int j = 0; j < 8; ++j) Vt[cur][vch * 16 + 8 + j][vrow] = vb2[j];

        short8 knext[4][2], vna, vnb;
        if (tt < 31) loadK(tt + 1, knext);
        if (tt < by) {
            const short* vp = vb_base + (size_t)((tt + 1) * 64 + vrow) * LD;
            vna = *(const short8*)vp; vnb = *(const short8*)(vp + 8);
        }

        int t0 = tt * 64;
        f32x4 sacc[4];
#pragma unroll
        for (int ni = 0; ni < 4; ++ni) {
            sacc[ni] = (f32x4){0.f, 0.f, 0.f, 0.f};
            sacc[ni] = __builtin_amdgcn_mfma_f32_16x16x32_bf16(kcur[ni][0], q0, sacc[ni], 0, 0, 0);
            sacc[ni] = __builtin_amdgcn_mfma_f32_16x16x32_bf16(kcur[ni][1], q1, sacc[ni], 0, 0, 0);
        }
#pragma unroll
        for (int ni = 0; ni < 4; ++ni)
            __builtin_nontemporal_store(sacc[ni],
                (f32x4*)&heat[((size_t)hb * S + sglob) * S + t0 + ni * 16 + g4]);

        float tm = -1e30f;
        if (tt == by) {
#pragma unroll
            for (int ni = 0; ni < 4; ++ni)
#pragma unroll
                for (int r = 0; r < 4; ++r) {
                    int t = t0 + ni * 16 + g4 + r;
                    float v = (t <= sglob) ? sacc[ni][r] : -1e30f;
                    sacc[ni][r] = v;
                    tm = fmaxf(tm, v);
                }
        } else {
#pragma unroll
            for (int ni = 0; ni < 4; ++ni)
#pragma unroll
                for (int r = 0; r < 4; ++r)
                    tm = fmaxf(tm, sacc[ni][r]);
        }
        tm = fmaxf(tm, __shfl_xor(tm, 16));
        tm = fmaxf(tm, __shfl_xor(tm, 32));

        float mn = fmaxf(m_run, tm);
        float sc = __expf(m_run - mn);
        m_run = mn;
        float ps = 0.f;
#pragma unroll
        for (int ni = 0; ni < 4; ++ni)
#pragma unroll
            for (int r = 0; r < 4; ++r) {
                float p = __expf(sacc[ni][r] - mn);
                sacc[ni][r] = p;
                ps += p;
            }
        ps += __shfl_xor(ps, 16);
        ps += __shfl_xor(ps, 32);
        l_run = l_run * sc + ps;

        float scr[4];
#pragma unroll
        for (int r = 0; r < 4; ++r) scr[r] = __shfl(sc, g4 + r, 64);
#pragma unroll
        for (int ni = 0; ni < 4; ++ni)
#pragma unroll
            for (int r = 0; r < 4; ++r)
                o[ni][r] *= scr[r];

#pragma unroll
        for (int ni = 0; ni < 4; ++ni) {
            short4 pw;
            pw.x = f2bf(sacc[ni][0]); pw.y = f2bf(sacc[ni][1]);
            pw.z = f2bf(sacc[ni][2]); pw.w = f2bf(sacc[ni][3]);
            *reinterpret_cast<short4*>(&Pl[wid][c][ni * 16 + g4]) = pw;
        }

        __syncthreads();

        short8 pa0 = *reinterpret_cast<const short8*>(&Pl[wid][c][g * 8]);
        short8 pa1 = *reinterpret_cast<const short8*>(&Pl[wid][c][32 + g * 8]);
#pragma unroll
        for (int ni = 0; ni < 4; ++ni) {
            short8 vb0 = *reinterpret_cast<const short8*>(&Vt[cur][ni * 16 + c][g * 8]);
            short8 vb1 = *reinterpret_cast<const short8*>(&Vt[cur][ni * 16 + c][32 + g * 8]);
            o[ni] = __builtin_amdgcn_mfma_f32_16x16x32_bf16(pa0, vb0, o[ni], 0, 0, 0);
            o[ni] = __builtin_amdgcn_mfma_f32_16x16x32_bf16(pa1, vb1, o[ni], 0, 0, 0);
        }

        if (tt < 31) {
#pragma unroll
            for (int ni = 0; ni < 4; ++ni)
#pragma unroll
                for (int kc = 0; kc < 2; ++kc)
                    kcur[ni][kc] = knext[ni][kc];
        }
        if (tt < by) { va = vna; vb2 = vnb; }
    }

    // ---- score-only phase: barrier-free streaming ----
    for (int tt = by + 1; tt < 32; ++tt) {
        int t0 = tt * 64;
        short8 knext[4][2];
        if (tt < 31) loadK(tt + 1, knext);
        f32x4 sacc[4];
#pragma unroll
        for (int ni = 0; ni < 4; ++ni) {
            sacc[ni] = (f32x4){0.f, 0.f, 0.f, 0.f};
            sacc[ni] = __builtin_amdgcn_mfma_f32_16x16x32_bf16(kcur[ni][0], q0, sacc[ni], 0, 0, 0);
            sacc[ni] = __builtin_amdgcn_mfma_f32_16x16x32_bf16(kcur[ni][1], q1, sacc[ni], 0, 0, 0);
        }
#pragma unroll
        for (int ni = 0; ni < 4; ++ni)
            __builtin_nontemporal_store(sacc[ni],
                (f32x4*)&heat[((size_t)hb * S + sglob) * S + t0 + ni * 16 + g4]);
        if (tt < 31) {
#pragma unroll
            for (int ni = 0; ni < 4; ++ni)
#pragma unroll
                for (int kc = 0; kc < 2; ++kc)
                    kcur[ni][kc] = knext[ni][kc];
        }
    }

    float linv[4];
#pragma unroll
    for (int r = 0; r < 4; ++r) linv[r] = 1.0f / __shfl(l_run, g4 + r, 64);
#pragma unroll
    for (int ni = 0; ni < 4; ++ni)
#pragma unroll
        for (int r = 0; r < 4; ++r) {
            float v = o[ni][r] * linv[r];
            wv[(size_t)(b * S + sbase + g4 + r) * 512 + h * 64 + ni * 16 + c] = f2bf(v);
        }
}

// ---------------------------------------------------------------------------
// LayerNorm over last dim 512; optional secondary bf16 output.
// ---------------------------------------------------------------------------
__device__ __forceinline__ float block_sum256(float v, float* sm) {
#pragma unroll
    for (int off = 32; off; off >>= 1) v += __shfl_down(v, off);
    __syncthreads();
    if ((threadIdx.x & 63) == 0) sm[threadIdx.x >> 6] = v;
    __syncthreads();
    return sm[0] + sm[1] + sm[2] + sm[3];
}

__global__ __launch_bounds__(256) void ln_kernel(
    const float* __restrict__ in, const float* __restrict__ g,
    const float* __restrict__ bta, float* __restrict__ outf,
    short* __restrict__ outb)
{
    __shared__ float sm[4];
    int row = blockIdx.x, tid = threadIdx.x;
    const float* r = in + (size_t)row * 512;
    float v0 = r[tid], v1 = r[tid + 256];
    float mu = block_sum256(v0 + v1, sm) * (1.f / 512.f);
    float d0 = v0 - mu, d1 = v1 - mu;
    float var = block_sum256(d0 * d0 + d1 * d1, sm) * (1.f / 512.f);
    float rs = rsqrtf(var + 1e-5f);
    float o0 = d0 * rs * g[tid] + bta[tid];
    float o1 = d1 * rs * g[tid + 256] + bta[tid + 256];
    outf[(size_t)row * 512 + tid]       = o0;
    outf[(size_t)row * 512 + tid + 256] = o1;
    if (outb) {
        outb[(size_t)row * 512 + tid]       = f2bf(o0);
        outb[(size_t)row * 512 + tid + 256] = f2bf(o1);
    }
}

// ---------------------------------------------------------------------------
extern "C" void kernel_launch(void* const* d_in, const int* in_sizes, int n_in,
                              void* d_out, int out_size, void* d_ws, size_t ws_size,
                              hipStream_t stream)
{
    const float* x    = (const float*)d_in[0];
    const float* Wq   = (const float*)d_in[1];
    const float* bq   = (const float*)d_in[2];
    const float* Wk   = (const float*)d_in[3];
    const float* bk   = (const float*)d_in[4];
    const float* Wv   = (const float*)d_in[5];
    const float* bv   = (const float*)d_in[6];
    const float* Wo   = (const float*)d_in[7];
    const float* bo   = (const float*)d_in[8];
    const float* W1   = (const float*)d_in[9];
    const float* b1   = (const float*)d_in[10];
    const float* W2   = (const float*)d_in[11];
    const float* b2   = (const float*)d_in[12];
    const float* ln1g = (const float*)d_in[13];
    const float* ln1b = (const float*)d_in[14];
    const float* ln2g = (const float*)d_in[15];
    const float* ln2b = (const float*)d_in[16];

    const int T = 4096;

    char* w = (char*)d_ws;
    short* xb     = (short*)(w);                     // 4096x512 bf16
    short* QKVb   = (short*)(w + 4194304);           // 4096x1536 bf16
    short* wvb    = (short*)(w + 16777216);          // 4096x512 bf16
    float* tmpf   = (float*)(w + 20971520);          // 4096x512 f32
    float* x1f    = (float*)(w + 29360128);          // 4096x512 f32
    short* x1b    = (short*)(w + 37748736);          // 4096x512 bf16
    short* Wqkv_t = (short*)(w + 41943040);          // 1536x512 bf16
    short* Wo_t   = (short*)(w + 43515904);          // 512x512 bf16
    short* W1_t   = (short*)(w + 44040192);          // 2048x512 bf16
    short* W2_t   = (short*)(w + 46137344);          // 512x2048 bf16
    float* qbias  = (float*)(w + 48234496);          // 1536 f32
    short* hidb   = (short*)(w);                     // 4096x2048 bf16 (aliases xb+QKVb, dead then)

    float* out_x2 = (float*)d_out;
    float* heat   = out_x2 + (size_t)T * 512;

    prep_kernel<<<dim3(5126), 256, 0, stream>>>(
        x, xb, Wq, Wk, Wv, Wo, W1, W2,
        Wqkv_t, Wo_t, W1_t, W2_t, bq, bk, bv, qbias);

    // QKV projection (combined, N=1536): 128x128 tiles
    gemm2<4, 4><<<dim3(32, 12), 256, 0, stream>>>(
        xb, 512, Wqkv_t, 512, qbias, nullptr, nullptr, QKVb, 1536, 512, 0);

    // fused attention + heatmap
    attn_kernel<<<dim3(512), 256, 0, stream>>>(QKVb, heat, wvb);

    // Wo projection + residual: 64x64 tiles (occupancy)
    gemm2<2, 2><<<dim3(64, 8), 256, 0, stream>>>(
        wvb, 512, Wo_t, 512, bo, x, tmpf, nullptr, 512, 512, 0);
    ln_kernel<<<dim3(T), 256, 0, stream>>>(tmpf, ln1g, ln1b, x1f, x1b);

    // FFN1: 128x128 tiles
    gemm2<4, 4><<<dim3(32, 16), 256, 0, stream>>>(
        x1b, 512, W1_t, 512, b1, nullptr, nullptr, hidb, 2048, 512, 1);
    // FFN2 + residual: 64x64 tiles
    gemm2<2, 2><<<dim3(64, 8), 256, 0, stream>>>(
        hidb, 2048, W2_t, 2048, b2, x1f, tmpf, nullptr, 512, 2048, 0);
    ln_kernel<<<dim3(T), 256, 0, stream>>>(tmpf, ln2g, ln2b, out_x2, nullptr);
}